// Round 1
// baseline (30.652 us; speedup 1.0000x reference)
//
#include <hip/hip_runtime.h>

// Problem constants (from reference): B=128, TX=400, ENC=512, DEC=512.
// Key insight: jax.nn.softmax over a size-1 axis => alpha == 1 everywhere.
//   Output 0: context[b, e] = sum_tx a[b, tx, e]          (B*ENC  = 65536 floats)
//   Output 1: alpha[b, tx]  = 1.0f                        (B*TX   = 51200 floats)
// Everything else in the reference (Wmat, tanh, coverage, v, w, b) is dead code.

#define BB   128
#define TXX  400
#define ENCC 512
#define TXC  8            // tx chunks per batch
#define TX_PER (TXX / TXC) // 50

// Kernel 1: initialize output. context part -> 0 (accumulated into by kernel 2),
// alpha part -> 1.0. Must run every call (harness does not re-poison between replays).
__global__ void init_out_kernel(float* __restrict__ out) {
    int i = blockIdx.x * blockDim.x + threadIdx.x;
    const int ctx_n = BB * ENCC;          // 65536
    const int total = ctx_n + BB * TXX;   // 116736
    if (i < total) {
        out[i] = (i < ctx_n) ? 0.0f : 1.0f;
    }
}

// Kernel 2: partial sums of a over tx, accumulated via atomicAdd.
// Grid: BB * TXC = 1024 blocks, 128 threads each.
// Each block: one (batch, tx-chunk) pair; thread t owns float4 at e = 4*t.
// Loads: 128 lanes x 16B = 2KB per tx row (contiguous, coalesced).
__global__ __launch_bounds__(128) void ctx_sum_kernel(const float* __restrict__ a,
                                                      float* __restrict__ out) {
    const int b   = blockIdx.x >> 3;   // / TXC
    const int txc = blockIdx.x & 7;    // % TXC
    const int e   = threadIdx.x * 4;

    const float4* base = reinterpret_cast<const float4*>(
        a + ((size_t)b * TXX + (size_t)txc * TX_PER) * ENCC + e);
    const int row_stride_v4 = ENCC / 4; // 128 float4 per tx row

    float4 acc = make_float4(0.f, 0.f, 0.f, 0.f);
    #pragma unroll 5
    for (int t = 0; t < TX_PER; ++t) {
        float4 vv = base[(size_t)t * row_stride_v4];
        acc.x += vv.x; acc.y += vv.y; acc.z += vv.z; acc.w += vv.w;
    }

    float* o = out + b * ENCC + e;
    atomicAdd(o + 0, acc.x);
    atomicAdd(o + 1, acc.y);
    atomicAdd(o + 2, acc.z);
    atomicAdd(o + 3, acc.w);
}

extern "C" void kernel_launch(void* const* d_in, const int* in_sizes, int n_in,
                              void* d_out, int out_size, void* d_ws, size_t ws_size,
                              hipStream_t stream) {
    const float* a = (const float*)d_in[0];   // (B, TX, ENC) float32
    float* out = (float*)d_out;               // [context (B*ENC) | alpha (B*TX)]

    // 1) init: zeros for context accumulation, ones for alpha
    const int total = BB * ENCC + BB * TXX;   // 116736
    init_out_kernel<<<(total + 255) / 256, 256, 0, stream>>>(out);

    // 2) accumulate context = sum_tx a
    ctx_sum_kernel<<<BB * TXC, 128, 0, stream>>>(a, out);
}

// Round 2
// 20.800 us; speedup vs baseline: 1.4737x; 1.4737x over previous
//
#include <hip/hip_runtime.h>

// Problem constants (from reference): B=128, TX=400, ENC=512, DEC=512.
// Key insight: jax.nn.softmax over a size-1 axis => alpha == 1 everywhere.
//   Output 0: context[b, e] = sum_tx a[b, tx, e]          (B*ENC  = 65536 floats)
//   Output 1: alpha[b, tx]  = 1.0f                        (B*TX   = 51200 floats)
// Everything else in the reference (Wmat, tanh, coverage, v, w, b) is dead code.
//
// Single fused kernel, no atomics:
//   grid = B * ECHUNKS = 512 blocks; block (b, ec) exclusively owns
//   context[b, ec*128:(ec+1)*128] -> plain stores, no zero-init needed.
//   256 threads = 8 tx-groups x 32 float4-lanes; LDS tree-reduce over groups.
//   Each block also writes its private 100-element slice of alpha = 1.0f.

#define BB      128
#define TXX     400
#define ENCC    512
#define ECHUNKS 4
#define ECW     (ENCC / ECHUNKS)   // 128 floats per chunk
#define ECV     (ECW / 4)          // 32 float4 per chunk
#define GROUPS  8
#define TPB     (GROUPS * ECV)     // 256 threads
#define TX_PER  (TXX / GROUPS)     // 50 rows per group
#define ALPHA_PER ((BB * TXX) / (BB * ECHUNKS))  // 100 floats per block

__global__ __launch_bounds__(TPB) void bahdanau_fused_kernel(
        const float* __restrict__ a, float* __restrict__ out) {
    const int blk = blockIdx.x;
    const int b   = blk >> 2;          // / ECHUNKS
    const int ec  = blk & (ECHUNKS - 1);
    const int g   = threadIdx.x >> 5;  // tx group 0..7
    const int l   = threadIdx.x & 31;  // float4 lane within chunk

    // a viewed as float4: row stride = ENCC/4 = 128
    const float4* base = reinterpret_cast<const float4*>(a)
                       + (size_t)b * (TXX * (ENCC / 4))
                       + ec * ECV + l;

    float4 acc = make_float4(0.f, 0.f, 0.f, 0.f);
    #pragma unroll 10
    for (int k = 0; k < TX_PER; ++k) {
        float4 v = base[(size_t)(g + k * GROUPS) * (ENCC / 4)];
        acc.x += v.x; acc.y += v.y; acc.z += v.z; acc.w += v.w;
    }

    __shared__ float4 lds[TPB];
    lds[threadIdx.x] = acc;
    __syncthreads();

    // tree-reduce the 8 group-partials down to group 0
    #pragma unroll
    for (int s = TPB / 2; s >= ECV; s >>= 1) {
        if (threadIdx.x < s) {
            float4 o = lds[threadIdx.x + s];
            float4 m = lds[threadIdx.x];
            m.x += o.x; m.y += o.y; m.z += o.z; m.w += o.w;
            lds[threadIdx.x] = m;
        }
        __syncthreads();
    }

    if (threadIdx.x < ECV) {
        reinterpret_cast<float4*>(out + (size_t)b * ENCC + ec * ECW)[threadIdx.x]
            = lds[threadIdx.x];
    }

    // alpha = 1.0f; each block writes a private 100-float slice
    float* alpha = out + BB * ENCC;
    if (threadIdx.x < ALPHA_PER) {
        alpha[(size_t)blk * ALPHA_PER + threadIdx.x] = 1.0f;
    }
}

extern "C" void kernel_launch(void* const* d_in, const int* in_sizes, int n_in,
                              void* d_out, int out_size, void* d_ws, size_t ws_size,
                              hipStream_t stream) {
    const float* a = (const float*)d_in[0];   // (B, TX, ENC) float32
    float* out = (float*)d_out;               // [context (B*ENC) | alpha (B*TX)]

    bahdanau_fused_kernel<<<BB * ECHUNKS, TPB, 0, stream>>>(a, out);
}

// Round 4
// 19.163 us; speedup vs baseline: 1.5996x; 1.0854x over previous
//
#include <hip/hip_runtime.h>

// Problem constants (from reference): B=128, TX=400, ENC=512, DEC=512.
// Key insight: jax.nn.softmax over a size-1 axis => alpha == 1 everywhere.
//   Output 0: context[b, e] = sum_tx a[b, tx, e]          (B*ENC  = 65536 floats)
//   Output 1: alpha[b, tx]  = 1.0f                        (B*TX   = 51200 floats)
// Everything else in the reference (Wmat, tanh, coverage, v, w, b) is dead code.
//
// Single fused kernel, no atomics:
//   grid = B * ECHUNKS = 512 blocks; block (b, ec) exclusively owns
//   context[b, ec*128:(ec+1)*128] -> plain stores, no zero-init needed.
//   512 threads = 16 tx-groups x 32 float4-lanes (4 waves/SIMD at 2 blocks/CU
//   for latency hiding); LDS tree-reduce over groups. Non-temporal loads for
//   the read-once `a` stream (native ext_vector_type for the builtin).
//   Each block also writes its private 100-float slice of alpha (25 x float4).

#define BB      128
#define TXX     400
#define ENCC    512
#define ECHUNKS 4
#define ECW     (ENCC / ECHUNKS)   // 128 floats per chunk
#define ECV     (ECW / 4)          // 32 float4 per chunk
#define GROUPS  16
#define TPB     (GROUPS * ECV)     // 512 threads
#define TX_PER  (TXX / GROUPS)     // 25 rows per group
#define ALPHA_PER 100              // (BB*TXX)/(BB*ECHUNKS) floats per block

typedef float f32x4 __attribute__((ext_vector_type(4)));

__global__ __launch_bounds__(TPB) void bahdanau_fused_kernel(
        const float* __restrict__ a, float* __restrict__ out) {
    const int blk = blockIdx.x;
    const int b   = blk >> 2;          // / ECHUNKS
    const int ec  = blk & (ECHUNKS - 1);
    const int g   = threadIdx.x >> 5;  // tx group 0..15
    const int l   = threadIdx.x & 31;  // float4 lane within chunk

    // a viewed as f32x4: row stride = ENCC/4 = 128
    const f32x4* base = reinterpret_cast<const f32x4*>(a)
                      + (size_t)b * (TXX * (ENCC / 4))
                      + ec * ECV + l;

    f32x4 acc = (f32x4)(0.f);
    #pragma unroll
    for (int k = 0; k < TX_PER; ++k) {
        f32x4 v = __builtin_nontemporal_load(
            &base[(size_t)(g + k * GROUPS) * (ENCC / 4)]);
        acc += v;
    }

    __shared__ f32x4 lds[TPB];
    lds[threadIdx.x] = acc;
    __syncthreads();

    // tree-reduce the 16 group-partials down to group 0
    #pragma unroll
    for (int s = TPB / 2; s >= ECV; s >>= 1) {
        if (threadIdx.x < s) {
            lds[threadIdx.x] += lds[threadIdx.x + s];
        }
        __syncthreads();
    }

    if (threadIdx.x < ECV) {
        reinterpret_cast<f32x4*>(out + (size_t)b * ENCC + ec * ECW)[threadIdx.x]
            = lds[threadIdx.x];
    }

    // alpha = 1.0f; each block writes a private 100-float (25 f32x4) slice
    f32x4* alpha4 = reinterpret_cast<f32x4*>(out + BB * ENCC
                                             + (size_t)blk * ALPHA_PER);
    if (threadIdx.x < ALPHA_PER / 4) {
        alpha4[threadIdx.x] = (f32x4)(1.f);
    }
}

extern "C" void kernel_launch(void* const* d_in, const int* in_sizes, int n_in,
                              void* d_out, int out_size, void* d_ws, size_t ws_size,
                              hipStream_t stream) {
    const float* a = (const float*)d_in[0];   // (B, TX, ENC) float32
    float* out = (float*)d_out;               // [context (B*ENC) | alpha (B*TX)]

    bahdanau_fused_kernel<<<BB * ECHUNKS, TPB, 0, stream>>>(a, out);
}